// Round 2
// baseline (304.024 us; speedup 1.0000x reference)
//
#include <hip/hip_runtime.h>

#define N_USER 100000
#define N_ITEM 50000
#define NTOT   150000
#define D      64
#define NNZ    4000000
#define B      2048
#define NEG    8192
#define NSLOT  (B + B + NEG)   /* 12288 output rows */
#define CAP    128             /* bucket capacity; deg ~ Poisson(26.7), P(>=128) ~ e^-99 */

__device__ __forceinline__ int slot_row(int slot,
                                        const int* __restrict__ users,
                                        const int* __restrict__ pos,
                                        const int* __restrict__ neg) {
    if (slot < B)     return users[slot];
    if (slot < 2 * B) return N_USER + pos[slot - B];
    return N_USER + neg[slot - 2 * B];
}

__device__ __forceinline__ const float* e0_row(int c,
                                               const float* __restrict__ ue,
                                               const float* __restrict__ ie) {
    return (c < N_USER) ? &ue[(size_t)c * D] : &ie[(size_t)(c - N_USER) * D];
}

// ---------------------------------------------------------------------------
// Kernel 1: slotmap = -1, nuniq = 0  (ws is poisoned 0xAA every call)
// ---------------------------------------------------------------------------
__global__ void k_clear(int* __restrict__ slotmap, int* __restrict__ nuniq) {
    int i = blockIdx.x * blockDim.x + threadIdx.x;
    if (i < NTOT) slotmap[i] = -1;
    if (i == 0) *nuniq = 0;
}

// ---------------------------------------------------------------------------
// Kernel 2: dedupe needed rows -> dense ids; zero cnt + accd for claimed ids.
// One wave per output slot; lane 0 claims, wave zeroes the dense acc row.
// ---------------------------------------------------------------------------
__global__ void k_mark(const int* __restrict__ users,
                       const int* __restrict__ pos,
                       const int* __restrict__ neg,
                       int* __restrict__ slotmap,
                       int* __restrict__ nuniq,
                       int* __restrict__ cnt,
                       float* __restrict__ accd) {
    int wave = (blockIdx.x * blockDim.x + threadIdx.x) >> 6;
    int lane = threadIdx.x & 63;
    if (wave >= NSLOT) return;
    int r = slot_row(wave, users, pos, neg);
    int id = -1;
    if (lane == 0) {
        int old = atomicCAS(&slotmap[r], -1, -2);
        if (old == -1) {
            id = atomicAdd(nuniq, 1);
            cnt[id] = 0;
            atomicExch(&slotmap[r], id);   // publish final id
        }
    }
    id = __shfl(id, 0);
    if (id >= 0) accd[(size_t)id * D + lane] = 0.0f;
}

// ---------------------------------------------------------------------------
// Kernel 3: stream all edges; hit lanes append (col,val) to their row bucket.
// Only a 4-byte counter atomic per hit edge (no 256 B accumulator atomics).
// ---------------------------------------------------------------------------
__global__ void k_scan(const int*   __restrict__ adj_row,
                       const int*   __restrict__ adj_col,
                       const float* __restrict__ adj_val,
                       const float* __restrict__ ue,
                       const float* __restrict__ ie,
                       const int*   __restrict__ slotmap,
                       int*   __restrict__ cnt,
                       int*   __restrict__ bcol,
                       float* __restrict__ bval,
                       float* __restrict__ accd) {
    int tid = blockIdx.x * blockDim.x + threadIdx.x;
    int nth = gridDim.x * blockDim.x;
    for (int e = tid; e < NNZ; e += nth) {
        int r = adj_row[e];
        int s = slotmap[r];
        if (s >= 0) {
            int   c = adj_col[e];
            float v = adj_val[e];
            int idx = atomicAdd(&cnt[s], 1);
            if (idx < CAP) {
                bcol[s * CAP + idx] = c;
                bval[s * CAP + idx] = v;
            } else {
                // statistically impossible overflow; correct fallback
                const float* x = e0_row(c, ue, ie);
                for (int d = 0; d < D; ++d)
                    atomicAdd(&accd[(size_t)s * D + d], v * x[d]);
            }
        }
    }
}

// ---------------------------------------------------------------------------
// Kernel 4: one wave per unique row: register-accumulate its bucket, write once.
// 4-deep unroll keeps 4 independent 256 B gathers in flight per wave.
// ---------------------------------------------------------------------------
__global__ void k_rowacc(const int*   __restrict__ nuniq,
                         const int*   __restrict__ cnt,
                         const int*   __restrict__ bcol,
                         const float* __restrict__ bval,
                         const float* __restrict__ ue,
                         const float* __restrict__ ie,
                         float* __restrict__ accd) {
    int wave = (blockIdx.x * blockDim.x + threadIdx.x) >> 6;
    int lane = threadIdx.x & 63;
    if (wave >= *nuniq) return;
    int n = cnt[wave];
    if (n > CAP) n = CAP;
    const int*   bc = &bcol[wave * CAP];
    const float* bv = &bval[wave * CAP];
    float a = 0.0f;
    int i = 0;
    for (; i + 4 <= n; i += 4) {
        int c0 = bc[i], c1 = bc[i + 1], c2 = bc[i + 2], c3 = bc[i + 3];
        float v0 = bv[i], v1 = bv[i + 1], v2 = bv[i + 2], v3 = bv[i + 3];
        float x0 = e0_row(c0, ue, ie)[lane];
        float x1 = e0_row(c1, ue, ie)[lane];
        float x2 = e0_row(c2, ue, ie)[lane];
        float x3 = e0_row(c3, ue, ie)[lane];
        a += v0 * x0;
        a += v1 * x1;
        a += v2 * x2;
        a += v3 * x3;
    }
    for (; i < n; ++i) {
        int c = bc[i];
        float v = bv[i];
        a += v * e0_row(c, ue, ie)[lane];
    }
    accd[(size_t)wave * D + lane] += a;   // += keeps (never-taken) overflow contributions
}

// ---------------------------------------------------------------------------
// Kernel 5: out[slot] = 0.25*e0[r] + 0.75*accd[slotmap[r]]
// ---------------------------------------------------------------------------
__global__ void k_out(const int* __restrict__ users,
                      const int* __restrict__ pos,
                      const int* __restrict__ neg,
                      const float* __restrict__ ue,
                      const float* __restrict__ ie,
                      const int* __restrict__ slotmap,
                      const float* __restrict__ accd,
                      float* __restrict__ out) {
    int wave = (blockIdx.x * blockDim.x + threadIdx.x) >> 6;
    int lane = threadIdx.x & 63;
    if (wave >= NSLOT) return;
    int r = slot_row(wave, users, pos, neg);
    float e = (r < N_USER) ? ue[(size_t)r * D + lane]
                           : ie[(size_t)(r - N_USER) * D + lane];
    int id = slotmap[r];
    out[(size_t)wave * D + lane] = 0.25f * e + 0.75f * accd[(size_t)id * D + lane];
}

// ---------------------------------------------------------------------------
extern "C" void kernel_launch(void* const* d_in, const int* in_sizes, int n_in,
                              void* d_out, int out_size, void* d_ws, size_t ws_size,
                              hipStream_t stream) {
    const int*   users   = (const int*)  d_in[0];
    const int*   pos     = (const int*)  d_in[1];
    const int*   neg     = (const int*)  d_in[2];
    const float* ue      = (const float*)d_in[5];
    const float* ie      = (const float*)d_in[6];
    const int*   adj_row = (const int*)  d_in[7];
    const int*   adj_col = (const int*)  d_in[8];
    const float* adj_val = (const float*)d_in[9];
    float*       out     = (float*)      d_out;

    char* w = (char*)d_ws;
    int*   slotmap = (int*)w;                 w += (size_t)NTOT * sizeof(int);
    int*   nuniq   = (int*)w;                 w += 256;
    int*   cnt     = (int*)w;                 w += (size_t)NSLOT * sizeof(int);
    int*   bcol    = (int*)w;                 w += (size_t)NSLOT * CAP * sizeof(int);
    float* bval    = (float*)w;               w += (size_t)NSLOT * CAP * sizeof(float);
    float* accd    = (float*)w;               /* NSLOT * D floats */

    k_clear <<<(NTOT + 255) / 256, 256, 0, stream>>>(slotmap, nuniq);
    k_mark  <<<(NSLOT * 64 + 255) / 256, 256, 0, stream>>>(users, pos, neg,
                                                           slotmap, nuniq, cnt, accd);
    k_scan  <<<2048, 256, 0, stream>>>(adj_row, adj_col, adj_val, ue, ie,
                                       slotmap, cnt, bcol, bval, accd);
    k_rowacc<<<(NSLOT * 64 + 255) / 256, 256, 0, stream>>>(nuniq, cnt, bcol, bval,
                                                           ue, ie, accd);
    k_out   <<<(NSLOT * 64 + 255) / 256, 256, 0, stream>>>(users, pos, neg, ue, ie,
                                                           slotmap, accd, out);
}

// Round 3
// 194.714 us; speedup vs baseline: 1.5614x; 1.5614x over previous
//
#include <hip/hip_runtime.h>

#define N_USER 100000
#define N_ITEM 50000
#define NTOT   150000
#define D      64
#define NNZ    4000000
#define B      2048
#define NEG    8192
#define NSLOT  (B + B + NEG)   /* 12288 output rows */
#define CAP    128             /* deg ~ Poisson(26.7); P(>=128) ~ e^-99 */

__device__ __forceinline__ int slot_row(int slot,
                                        const int* __restrict__ users,
                                        const int* __restrict__ pos,
                                        const int* __restrict__ neg) {
    if (slot < B)     return users[slot];
    if (slot < 2 * B) return N_USER + pos[slot - B];
    return N_USER + neg[slot - 2 * B];
}

__device__ __forceinline__ const float* e0_row(int c,
                                               const float* __restrict__ ue,
                                               const float* __restrict__ ie) {
    return (c < N_USER) ? &ue[(size_t)c * D] : &ie[(size_t)(c - N_USER) * D];
}

// ---------------------------------------------------------------------------
// Kernel 1: slotmap = -1 (ws is poisoned 0xAA every call)
// ---------------------------------------------------------------------------
__global__ void k_clear(int* __restrict__ slotmap) {
    int i = blockIdx.x * blockDim.x + threadIdx.x;
    if (i < NTOT) slotmap[i] = -1;
}

// ---------------------------------------------------------------------------
// Kernel 2: claim rows. id := slot index of first claimer (distinct-address
// CAS, no shared counter). Winner wave zeroes cnt[slot] and accd[slot].
// ---------------------------------------------------------------------------
__global__ void k_mark(const int* __restrict__ users,
                       const int* __restrict__ pos,
                       const int* __restrict__ neg,
                       int* __restrict__ slotmap,
                       int* __restrict__ cnt,
                       float* __restrict__ accd) {
    int slot = (blockIdx.x * blockDim.x + threadIdx.x) >> 6;
    int lane = threadIdx.x & 63;
    if (slot >= NSLOT) return;
    int r = slot_row(slot, users, pos, neg);
    int old = 0;
    if (lane == 0) old = atomicCAS(&slotmap[r], -1, slot);
    old = __shfl(old, 0);
    if (old == -1) {                      // this slot won the row
        if (lane == 0) cnt[slot] = 0;
        accd[(size_t)slot * D + lane] = 0.0f;
    }
}

// ---------------------------------------------------------------------------
// Kernel 3: stream all edges; hit lanes append (col,val) to the owning
// slot's bucket. Only a 4 B counter atomic per hit edge.
// ---------------------------------------------------------------------------
__global__ void k_scan(const int*   __restrict__ adj_row,
                       const int*   __restrict__ adj_col,
                       const float* __restrict__ adj_val,
                       const float* __restrict__ ue,
                       const float* __restrict__ ie,
                       const int*   __restrict__ slotmap,
                       int*   __restrict__ cnt,
                       int*   __restrict__ bcol,
                       float* __restrict__ bval,
                       float* __restrict__ accd) {
    int tid = blockIdx.x * blockDim.x + threadIdx.x;
    int nth = gridDim.x * blockDim.x;
    for (int e = tid; e < NNZ; e += nth) {
        int r = adj_row[e];
        int s = slotmap[r];
        if (s >= 0) {
            int   c = adj_col[e];
            float v = adj_val[e];
            int idx = atomicAdd(&cnt[s], 1);
            if (idx < CAP) {
                bcol[s * CAP + idx] = c;
                bval[s * CAP + idx] = v;
            } else {
                // statistically impossible overflow; correct fallback
                const float* x = e0_row(c, ue, ie);
                for (int d = 0; d < D; ++d)
                    atomicAdd(&accd[(size_t)s * D + d], v * x[d]);
            }
        }
    }
}

// ---------------------------------------------------------------------------
// Kernel 4: one wave per slot; winners accumulate their bucket in registers
// (4-deep independent gathers from L3-resident e0) and write the row once.
// ---------------------------------------------------------------------------
__global__ void k_rowacc(const int* __restrict__ users,
                         const int* __restrict__ pos,
                         const int* __restrict__ neg,
                         const int* __restrict__ slotmap,
                         const int* __restrict__ cnt,
                         const int* __restrict__ bcol,
                         const float* __restrict__ bval,
                         const float* __restrict__ ue,
                         const float* __restrict__ ie,
                         float* __restrict__ accd) {
    int slot = (blockIdx.x * blockDim.x + threadIdx.x) >> 6;
    int lane = threadIdx.x & 63;
    if (slot >= NSLOT) return;
    int r = slot_row(slot, users, pos, neg);
    if (slotmap[r] != slot) return;       // not the owning slot
    int n = cnt[slot];
    if (n > CAP) n = CAP;
    const int*   bc = &bcol[slot * CAP];
    const float* bv = &bval[slot * CAP];
    float a = 0.0f;
    int i = 0;
    for (; i + 4 <= n; i += 4) {
        int c0 = bc[i], c1 = bc[i + 1], c2 = bc[i + 2], c3 = bc[i + 3];
        float v0 = bv[i], v1 = bv[i + 1], v2 = bv[i + 2], v3 = bv[i + 3];
        float x0 = e0_row(c0, ue, ie)[lane];
        float x1 = e0_row(c1, ue, ie)[lane];
        float x2 = e0_row(c2, ue, ie)[lane];
        float x3 = e0_row(c3, ue, ie)[lane];
        a += v0 * x0;
        a += v1 * x1;
        a += v2 * x2;
        a += v3 * x3;
    }
    for (; i < n; ++i) a += bv[i] * e0_row(bc[i], ue, ie)[lane];
    accd[(size_t)slot * D + lane] += a;   // += keeps (never-taken) overflow adds
}

// ---------------------------------------------------------------------------
// Kernel 5: out[slot] = 0.25*e0[r] + 0.75*accd[slotmap[r]]
// ---------------------------------------------------------------------------
__global__ void k_out(const int* __restrict__ users,
                      const int* __restrict__ pos,
                      const int* __restrict__ neg,
                      const float* __restrict__ ue,
                      const float* __restrict__ ie,
                      const int* __restrict__ slotmap,
                      const float* __restrict__ accd,
                      float* __restrict__ out) {
    int slot = (blockIdx.x * blockDim.x + threadIdx.x) >> 6;
    int lane = threadIdx.x & 63;
    if (slot >= NSLOT) return;
    int r = slot_row(slot, users, pos, neg);
    float e = (r < N_USER) ? ue[(size_t)r * D + lane]
                           : ie[(size_t)(r - N_USER) * D + lane];
    int id = slotmap[r];
    out[(size_t)slot * D + lane] = 0.25f * e + 0.75f * accd[(size_t)id * D + lane];
}

// ---------------------------------------------------------------------------
extern "C" void kernel_launch(void* const* d_in, const int* in_sizes, int n_in,
                              void* d_out, int out_size, void* d_ws, size_t ws_size,
                              hipStream_t stream) {
    const int*   users   = (const int*)  d_in[0];
    const int*   pos     = (const int*)  d_in[1];
    const int*   neg     = (const int*)  d_in[2];
    const float* ue      = (const float*)d_in[5];
    const float* ie      = (const float*)d_in[6];
    const int*   adj_row = (const int*)  d_in[7];
    const int*   adj_col = (const int*)  d_in[8];
    const float* adj_val = (const float*)d_in[9];
    float*       out     = (float*)      d_out;

    char* w = (char*)d_ws;
    int*   slotmap = (int*)w;   w += (size_t)NTOT * sizeof(int);
    int*   cnt     = (int*)w;   w += (size_t)NSLOT * sizeof(int);
    int*   bcol    = (int*)w;   w += (size_t)NSLOT * CAP * sizeof(int);
    float* bval    = (float*)w; w += (size_t)NSLOT * CAP * sizeof(float);
    float* accd    = (float*)w; /* NSLOT * D floats */

    k_clear <<<(NTOT + 255) / 256, 256, 0, stream>>>(slotmap);
    k_mark  <<<(NSLOT * 64 + 255) / 256, 256, 0, stream>>>(users, pos, neg,
                                                           slotmap, cnt, accd);
    k_scan  <<<2048, 256, 0, stream>>>(adj_row, adj_col, adj_val, ue, ie,
                                       slotmap, cnt, bcol, bval, accd);
    k_rowacc<<<(NSLOT * 64 + 255) / 256, 256, 0, stream>>>(users, pos, neg,
                                                           slotmap, cnt, bcol, bval,
                                                           ue, ie, accd);
    k_out   <<<(NSLOT * 64 + 255) / 256, 256, 0, stream>>>(users, pos, neg, ue, ie,
                                                           slotmap, accd, out);
}

// Round 4
// 170.865 us; speedup vs baseline: 1.7793x; 1.1396x over previous
//
#include <hip/hip_runtime.h>

#define N_USER 100000
#define N_ITEM 50000
#define NTOT   150000
#define D      64
#define NNZ    4000000
#define B      2048
#define NEG    8192
#define NSLOT  (B + B + NEG)        /* 12288 output rows */
#define CAP    128                  /* deg ~ Poisson(26.7); P(>=128) ~ e^-99 */
#define NBW    ((NTOT + 31) / 32)   /* 4688 bitmap words (18.75 KB) */

__device__ __forceinline__ int slot_row(int slot,
                                        const int* __restrict__ users,
                                        const int* __restrict__ pos,
                                        const int* __restrict__ neg) {
    if (slot < B)     return users[slot];
    if (slot < 2 * B) return N_USER + pos[slot - B];
    return N_USER + neg[slot - 2 * B];
}

__device__ __forceinline__ const float* e0_row(int c,
                                               const float* __restrict__ ue,
                                               const float* __restrict__ ie) {
    return (c < N_USER) ? &ue[(size_t)c * D] : &ie[(size_t)(c - N_USER) * D];
}

// ---------------------------------------------------------------------------
// Kernel 1: slotmap = -1, bitmap = 0 (ws is poisoned 0xAA every call)
// ---------------------------------------------------------------------------
__global__ void k_clear(int* __restrict__ slotmap, unsigned int* __restrict__ bits) {
    int i = blockIdx.x * blockDim.x + threadIdx.x;
    if (i < NTOT) slotmap[i] = -1;
    if (i < NBW)  bits[i] = 0u;
}

// ---------------------------------------------------------------------------
// Kernel 2: claim rows (distinct-address CAS, id = claiming slot index).
// Winner wave zeroes cnt[slot], accd[slot], and sets the row's bitmap bit.
// ---------------------------------------------------------------------------
__global__ void k_mark(const int* __restrict__ users,
                       const int* __restrict__ pos,
                       const int* __restrict__ neg,
                       int* __restrict__ slotmap,
                       unsigned int* __restrict__ bits,
                       int* __restrict__ cnt,
                       float* __restrict__ accd) {
    int slot = (blockIdx.x * blockDim.x + threadIdx.x) >> 6;
    int lane = threadIdx.x & 63;
    if (slot >= NSLOT) return;
    int r = slot_row(slot, users, pos, neg);
    int old = 0;
    if (lane == 0) old = atomicCAS(&slotmap[r], -1, slot);
    old = __shfl(old, 0);
    if (old == -1) {                      // this slot won the row
        if (lane == 0) {
            cnt[slot] = 0;
            atomicOr(&bits[r >> 5], 1u << (r & 31));
        }
        accd[(size_t)slot * D + lane] = 0.0f;
    }
}

// ---------------------------------------------------------------------------
// Kernel 3: stream all edges with int4/float4 loads; per-block LDS bitmap
// filter; hit edges (7.5%) do one random slotmap load + one packed 8 B
// bucket store. Only a 4 B counter atomic per hit edge.
// ---------------------------------------------------------------------------
__global__ void k_scan(const int*   __restrict__ adj_row,
                       const int*   __restrict__ adj_col,
                       const float* __restrict__ adj_val,
                       const float* __restrict__ ue,
                       const float* __restrict__ ie,
                       const unsigned int* __restrict__ bits,
                       const int*   __restrict__ slotmap,
                       int*   __restrict__ cnt,
                       int2*  __restrict__ bcv,
                       float* __restrict__ accd) {
    __shared__ unsigned int sbits[NBW];
    {   // cooperative 16 B copy of the bitmap into LDS (NBW = 4688 = 1172*4)
        const int4* gb = (const int4*)bits;
        int4* sb = (int4*)sbits;
        for (int i = threadIdx.x; i < NBW / 4; i += blockDim.x) sb[i] = gb[i];
    }
    __syncthreads();

    int tid = blockIdx.x * blockDim.x + threadIdx.x;
    int nth = gridDim.x * blockDim.x;
    const int4*   row4 = (const int4*)adj_row;
    const int4*   col4 = (const int4*)adj_col;
    const float4* val4 = (const float4*)adj_val;

    for (int g = tid; g < NNZ / 4; g += nth) {
        int4   r = row4[g];
        int4   c = col4[g];
        float4 v = val4[g];
        #define PROC(RR, CC, VV)                                               \
        {                                                                      \
            unsigned int w = sbits[(RR) >> 5];                                 \
            if ((w >> ((RR) & 31)) & 1u) {                                     \
                int s = slotmap[RR];                                           \
                int idx = atomicAdd(&cnt[s], 1);                               \
                if (idx < CAP) {                                               \
                    bcv[s * CAP + idx] = make_int2(CC, __float_as_int(VV));    \
                } else { /* statistically impossible; correct fallback */      \
                    const float* x = e0_row(CC, ue, ie);                       \
                    for (int d = 0; d < D; ++d)                                \
                        atomicAdd(&accd[(size_t)s * D + d], (VV) * x[d]);      \
                }                                                              \
            }                                                                  \
        }
        PROC(r.x, c.x, v.x)
        PROC(r.y, c.y, v.y)
        PROC(r.z, c.z, v.z)
        PROC(r.w, c.w, v.w)
        #undef PROC
    }
}

// ---------------------------------------------------------------------------
// Kernel 4: one wave per slot; winners accumulate their bucket in registers
// (8-deep independent gathers from L3-resident e0) and write the row once.
// ---------------------------------------------------------------------------
__global__ void k_rowacc(const int* __restrict__ users,
                         const int* __restrict__ pos,
                         const int* __restrict__ neg,
                         const int* __restrict__ slotmap,
                         const int* __restrict__ cnt,
                         const int2* __restrict__ bcv,
                         const float* __restrict__ ue,
                         const float* __restrict__ ie,
                         float* __restrict__ accd) {
    int slot = (blockIdx.x * blockDim.x + threadIdx.x) >> 6;
    int lane = threadIdx.x & 63;
    if (slot >= NSLOT) return;
    int r = slot_row(slot, users, pos, neg);
    if (slotmap[r] != slot) return;       // not the owning slot
    int n = cnt[slot];
    if (n > CAP) n = CAP;
    const int2* bb = &bcv[slot * CAP];
    float a = 0.0f;
    int i = 0;
    for (; i + 8 <= n; i += 8) {
        int2 p0 = bb[i],     p1 = bb[i + 1], p2 = bb[i + 2], p3 = bb[i + 3];
        int2 p4 = bb[i + 4], p5 = bb[i + 5], p6 = bb[i + 6], p7 = bb[i + 7];
        float x0 = e0_row(p0.x, ue, ie)[lane];
        float x1 = e0_row(p1.x, ue, ie)[lane];
        float x2 = e0_row(p2.x, ue, ie)[lane];
        float x3 = e0_row(p3.x, ue, ie)[lane];
        float x4 = e0_row(p4.x, ue, ie)[lane];
        float x5 = e0_row(p5.x, ue, ie)[lane];
        float x6 = e0_row(p6.x, ue, ie)[lane];
        float x7 = e0_row(p7.x, ue, ie)[lane];
        a += __int_as_float(p0.y) * x0;
        a += __int_as_float(p1.y) * x1;
        a += __int_as_float(p2.y) * x2;
        a += __int_as_float(p3.y) * x3;
        a += __int_as_float(p4.y) * x4;
        a += __int_as_float(p5.y) * x5;
        a += __int_as_float(p6.y) * x6;
        a += __int_as_float(p7.y) * x7;
    }
    for (; i < n; ++i) {
        int2 p = bb[i];
        a += __int_as_float(p.y) * e0_row(p.x, ue, ie)[lane];
    }
    accd[(size_t)slot * D + lane] += a;   // += keeps (never-taken) overflow adds
}

// ---------------------------------------------------------------------------
// Kernel 5: out[slot] = 0.25*e0[r] + 0.75*accd[slotmap[r]]
// ---------------------------------------------------------------------------
__global__ void k_out(const int* __restrict__ users,
                      const int* __restrict__ pos,
                      const int* __restrict__ neg,
                      const float* __restrict__ ue,
                      const float* __restrict__ ie,
                      const int* __restrict__ slotmap,
                      const float* __restrict__ accd,
                      float* __restrict__ out) {
    int slot = (blockIdx.x * blockDim.x + threadIdx.x) >> 6;
    int lane = threadIdx.x & 63;
    if (slot >= NSLOT) return;
    int r = slot_row(slot, users, pos, neg);
    float e = (r < N_USER) ? ue[(size_t)r * D + lane]
                           : ie[(size_t)(r - N_USER) * D + lane];
    int id = slotmap[r];
    out[(size_t)slot * D + lane] = 0.25f * e + 0.75f * accd[(size_t)id * D + lane];
}

// ---------------------------------------------------------------------------
extern "C" void kernel_launch(void* const* d_in, const int* in_sizes, int n_in,
                              void* d_out, int out_size, void* d_ws, size_t ws_size,
                              hipStream_t stream) {
    const int*   users   = (const int*)  d_in[0];
    const int*   pos     = (const int*)  d_in[1];
    const int*   neg     = (const int*)  d_in[2];
    const float* ue      = (const float*)d_in[5];
    const float* ie      = (const float*)d_in[6];
    const int*   adj_row = (const int*)  d_in[7];
    const int*   adj_col = (const int*)  d_in[8];
    const float* adj_val = (const float*)d_in[9];
    float*       out     = (float*)      d_out;

    char* w = (char*)d_ws;
    int*          slotmap = (int*)w;          w += (size_t)NTOT * sizeof(int);
    unsigned int* bits    = (unsigned int*)w; w += (size_t)NBW * sizeof(unsigned int);
    int*          cnt     = (int*)w;          w += (size_t)NSLOT * sizeof(int);
    int2*         bcv     = (int2*)w;         w += (size_t)NSLOT * CAP * sizeof(int2);
    float*        accd    = (float*)w;        /* NSLOT * D floats */

    k_clear <<<(NTOT + 255) / 256, 256, 0, stream>>>(slotmap, bits);
    k_mark  <<<(NSLOT * 64 + 255) / 256, 256, 0, stream>>>(users, pos, neg,
                                                           slotmap, bits, cnt, accd);
    k_scan  <<<2048, 256, 0, stream>>>(adj_row, adj_col, adj_val, ue, ie,
                                       bits, slotmap, cnt, bcv, accd);
    k_rowacc<<<(NSLOT * 64 + 255) / 256, 256, 0, stream>>>(users, pos, neg,
                                                           slotmap, cnt, bcv,
                                                           ue, ie, accd);
    k_out   <<<(NSLOT * 64 + 255) / 256, 256, 0, stream>>>(users, pos, neg, ue, ie,
                                                           slotmap, accd, out);
}

// Round 5
// 163.209 us; speedup vs baseline: 1.8628x; 1.0469x over previous
//
#include <hip/hip_runtime.h>

#define N_USER 100000
#define N_ITEM 50000
#define NTOT   150000
#define D      64
#define NNZ    4000000
#define NQ     (NNZ / 4)
#define B      2048
#define NEG    8192
#define NSLOT  (B + B + NEG)        /* 12288 output rows */
#define CAP    128                  /* deg ~ Poisson(26.7); P(>=128) ~ e^-99 */
#define NBW    ((NTOT + 31) / 32)   /* 4688 bitmap words (18.75 KB) */

__device__ __forceinline__ int slot_row(int slot,
                                        const int* __restrict__ users,
                                        const int* __restrict__ pos,
                                        const int* __restrict__ neg) {
    if (slot < B)     return users[slot];
    if (slot < 2 * B) return N_USER + pos[slot - B];
    return N_USER + neg[slot - 2 * B];
}

__device__ __forceinline__ const float* e0_row(int c,
                                               const float* __restrict__ ue,
                                               const float* __restrict__ ie) {
    return (c < N_USER) ? &ue[(size_t)c * D] : &ie[(size_t)(c - N_USER) * D];
}

// ---------------------------------------------------------------------------
// Kernel 1: bits = 0 (only 18.75 KB now; claim happens on the bitmap itself)
// ---------------------------------------------------------------------------
__global__ void k_clear(unsigned int* __restrict__ bits) {
    int i = blockIdx.x * blockDim.x + threadIdx.x;
    if (i < NBW) bits[i] = 0u;
}

// ---------------------------------------------------------------------------
// Kernel 2: claim rows via atomicOr on the bitmap (old-value tells winner).
// Winner wave stores rowslot[r]=slot, zeroes cnt[slot] and accd[slot].
// ---------------------------------------------------------------------------
__global__ void k_mark(const int* __restrict__ users,
                       const int* __restrict__ pos,
                       const int* __restrict__ neg,
                       unsigned int* __restrict__ bits,
                       int* __restrict__ rowslot,
                       int* __restrict__ cnt,
                       float* __restrict__ accd) {
    int slot = (blockIdx.x * blockDim.x + threadIdx.x) >> 6;
    int lane = threadIdx.x & 63;
    if (slot >= NSLOT) return;
    int r = slot_row(slot, users, pos, neg);
    int won = 0;
    if (lane == 0) {
        unsigned int bit = 1u << (r & 31);
        unsigned int old = atomicOr(&bits[r >> 5], bit);
        won = (old & bit) ? 0 : 1;
        if (won) { rowslot[r] = slot; cnt[slot] = 0; }
    }
    won = __shfl(won, 0);
    if (won) accd[(size_t)slot * D + lane] = 0.0f;
}

// ---------------------------------------------------------------------------
// Kernel 3: stream all edges (int4/float4, 2-deep pipelined); LDS bitmap
// filter; hits (7.5%) do one random rowslot load + 4 B cnt atomic + 8 B store.
// 256 blocks x 1024 thr: bitmap-copy overhead 4.8 MB total, ~15 quads/thread.
// ---------------------------------------------------------------------------
__global__ __launch_bounds__(1024)
void k_scan(const int*   __restrict__ adj_row,
            const int*   __restrict__ adj_col,
            const float* __restrict__ adj_val,
            const float* __restrict__ ue,
            const float* __restrict__ ie,
            const unsigned int* __restrict__ bits,
            const int*   __restrict__ rowslot,
            int*   __restrict__ cnt,
            int2*  __restrict__ bcv,
            float* __restrict__ accd) {
    __shared__ unsigned int sbits[NBW];
    {   // cooperative 16 B copy of the bitmap into LDS (NBW/4 = 1172)
        const int4* gb = (const int4*)bits;
        int4* sb = (int4*)sbits;
        for (int i = threadIdx.x; i < NBW / 4; i += blockDim.x) sb[i] = gb[i];
    }
    __syncthreads();

    int tid = blockIdx.x * blockDim.x + threadIdx.x;
    int nth = gridDim.x * blockDim.x;
    const int4*   row4 = (const int4*)adj_row;
    const int4*   col4 = (const int4*)adj_col;
    const float4* val4 = (const float4*)adj_val;

    #define PROC(RR, CC, VV)                                               \
    {                                                                      \
        unsigned int w = sbits[(RR) >> 5];                                 \
        if ((w >> ((RR) & 31)) & 1u) {                                     \
            int s = rowslot[RR];                                           \
            int idx = atomicAdd(&cnt[s], 1);                               \
            if (idx < CAP) {                                               \
                bcv[(size_t)s * CAP + idx] = make_int2(CC, __float_as_int(VV)); \
            } else { /* statistically impossible; correct fallback */      \
                const float* x = e0_row(CC, ue, ie);                       \
                for (int d = 0; d < D; ++d)                                \
                    atomicAdd(&accd[(size_t)s * D + d], (VV) * x[d]);      \
            }                                                              \
        }                                                                  \
    }

    int g = tid;
    if (g >= NQ) return;
    int4   r = row4[g];
    int4   c = col4[g];
    float4 v = val4[g];
    for (;;) {
        int gn = g + nth;
        bool more = gn < NQ;
        int4 rn, cn; float4 vn;
        if (more) { rn = row4[gn]; cn = col4[gn]; vn = val4[gn]; }
        PROC(r.x, c.x, v.x)
        PROC(r.y, c.y, v.y)
        PROC(r.z, c.z, v.z)
        PROC(r.w, c.w, v.w)
        if (!more) break;
        g = gn; r = rn; c = cn; v = vn;
    }
    #undef PROC
}

// ---------------------------------------------------------------------------
// Kernel 4: one wave per slot; owner accumulates its bucket.
// Lane layout: grp = lane>>4 picks the bucket entry (4 concurrent),
// sub = lane&15 picks the float4 of the 256 B row. 16 entries in flight.
// Cross-group reduce via shfl_xor(16,32); grp 0 stores the row.
// ---------------------------------------------------------------------------
__global__ void k_rowacc(const int* __restrict__ users,
                         const int* __restrict__ pos,
                         const int* __restrict__ neg,
                         const int* __restrict__ rowslot,
                         const int* __restrict__ cnt,
                         const int2* __restrict__ bcv,
                         const float* __restrict__ ue,
                         const float* __restrict__ ie,
                         float* __restrict__ accd) {
    int slot = (blockIdx.x * blockDim.x + threadIdx.x) >> 6;
    int lane = threadIdx.x & 63;
    if (slot >= NSLOT) return;
    int r = slot_row(slot, users, pos, neg);
    if (rowslot[r] != slot) return;       // not the owning slot
    int n = cnt[slot];
    if (n > CAP) n = CAP;
    const int2* bb = &bcv[(size_t)slot * CAP];
    int sub = lane & 15, grp = lane >> 4;
    float4 a = make_float4(0.f, 0.f, 0.f, 0.f);
    for (int i = 0; i < n; i += 16) {
        int m  = n - 1;
        int e0 = i + grp, e1 = e0 + 4, e2 = e0 + 8, e3 = e0 + 12;
        int2 p0 = bb[min(e0, m)];
        int2 p1 = bb[min(e1, m)];
        int2 p2 = bb[min(e2, m)];
        int2 p3 = bb[min(e3, m)];
        float4 x0 = ((const float4*)e0_row(p0.x, ue, ie))[sub];
        float4 x1 = ((const float4*)e0_row(p1.x, ue, ie))[sub];
        float4 x2 = ((const float4*)e0_row(p2.x, ue, ie))[sub];
        float4 x3 = ((const float4*)e0_row(p3.x, ue, ie))[sub];
        float v0 = (e0 < n) ? __int_as_float(p0.y) : 0.f;
        float v1 = (e1 < n) ? __int_as_float(p1.y) : 0.f;
        float v2 = (e2 < n) ? __int_as_float(p2.y) : 0.f;
        float v3 = (e3 < n) ? __int_as_float(p3.y) : 0.f;
        a.x += v0 * x0.x; a.y += v0 * x0.y; a.z += v0 * x0.z; a.w += v0 * x0.w;
        a.x += v1 * x1.x; a.y += v1 * x1.y; a.z += v1 * x1.z; a.w += v1 * x1.w;
        a.x += v2 * x2.x; a.y += v2 * x2.y; a.z += v2 * x2.z; a.w += v2 * x2.w;
        a.x += v3 * x3.x; a.y += v3 * x3.y; a.z += v3 * x3.z; a.w += v3 * x3.w;
    }
    a.x += __shfl_xor(a.x, 16); a.y += __shfl_xor(a.y, 16);
    a.z += __shfl_xor(a.z, 16); a.w += __shfl_xor(a.w, 16);
    a.x += __shfl_xor(a.x, 32); a.y += __shfl_xor(a.y, 32);
    a.z += __shfl_xor(a.z, 32); a.w += __shfl_xor(a.w, 32);
    if (grp == 0) {
        float4* dst = (float4*)&accd[(size_t)slot * D];
        float4 o = dst[sub];   // += keeps (never-taken) overflow atomics
        dst[sub] = make_float4(o.x + a.x, o.y + a.y, o.z + a.z, o.w + a.w);
    }
}

// ---------------------------------------------------------------------------
// Kernel 5: out[slot] = 0.25*e0[r] + 0.75*accd[rowslot[r]]
// ---------------------------------------------------------------------------
__global__ void k_out(const int* __restrict__ users,
                      const int* __restrict__ pos,
                      const int* __restrict__ neg,
                      const float* __restrict__ ue,
                      const float* __restrict__ ie,
                      const int* __restrict__ rowslot,
                      const float* __restrict__ accd,
                      float* __restrict__ out) {
    int slot = (blockIdx.x * blockDim.x + threadIdx.x) >> 6;
    int lane = threadIdx.x & 63;
    if (slot >= NSLOT) return;
    int r = slot_row(slot, users, pos, neg);
    float e = (r < N_USER) ? ue[(size_t)r * D + lane]
                           : ie[(size_t)(r - N_USER) * D + lane];
    int id = rowslot[r];
    out[(size_t)slot * D + lane] = 0.25f * e + 0.75f * accd[(size_t)id * D + lane];
}

// ---------------------------------------------------------------------------
extern "C" void kernel_launch(void* const* d_in, const int* in_sizes, int n_in,
                              void* d_out, int out_size, void* d_ws, size_t ws_size,
                              hipStream_t stream) {
    const int*   users   = (const int*)  d_in[0];
    const int*   pos     = (const int*)  d_in[1];
    const int*   neg     = (const int*)  d_in[2];
    const float* ue      = (const float*)d_in[5];
    const float* ie      = (const float*)d_in[6];
    const int*   adj_row = (const int*)  d_in[7];
    const int*   adj_col = (const int*)  d_in[8];
    const float* adj_val = (const float*)d_in[9];
    float*       out     = (float*)      d_out;

    char* w = (char*)d_ws;
    int*          rowslot = (int*)w;          w += (size_t)NTOT * sizeof(int);
    unsigned int* bits    = (unsigned int*)w; w += (size_t)NBW * sizeof(unsigned int);
    int*          cnt     = (int*)w;          w += (size_t)NSLOT * sizeof(int);
    int2*         bcv     = (int2*)w;         w += (size_t)NSLOT * CAP * sizeof(int2);
    float*        accd    = (float*)w;        /* NSLOT * D floats */

    k_clear <<<(NBW + 255) / 256, 256, 0, stream>>>(bits);
    k_mark  <<<(NSLOT * 64 + 255) / 256, 256, 0, stream>>>(users, pos, neg,
                                                           bits, rowslot, cnt, accd);
    k_scan  <<<256, 1024, 0, stream>>>(adj_row, adj_col, adj_val, ue, ie,
                                       bits, rowslot, cnt, bcv, accd);
    k_rowacc<<<(NSLOT * 64 + 255) / 256, 256, 0, stream>>>(users, pos, neg,
                                                           rowslot, cnt, bcv,
                                                           ue, ie, accd);
    k_out   <<<(NSLOT * 64 + 255) / 256, 256, 0, stream>>>(users, pos, neg, ue, ie,
                                                           rowslot, accd, out);
}

// Round 6
// 158.765 us; speedup vs baseline: 1.9149x; 1.0280x over previous
//
#include <hip/hip_runtime.h>

#define N_USER 100000
#define N_ITEM 50000
#define NTOT   150000
#define D      64
#define NNZ    4000000
#define NQ     (NNZ / 4)
#define B      2048
#define NEG    8192
#define NSLOT  (B + B + NEG)        /* 12288 output rows */
#define CAP    128                  /* deg ~ Poisson(26.7); P(>=128) < 1e-40 */
#define NBW    ((NTOT + 31) / 32)   /* 4688 bitmap words (18.75 KB) */

__device__ __forceinline__ int slot_row(int slot,
                                        const int* __restrict__ users,
                                        const int* __restrict__ pos,
                                        const int* __restrict__ neg) {
    if (slot < B)     return users[slot];
    if (slot < 2 * B) return N_USER + pos[slot - B];
    return N_USER + neg[slot - 2 * B];
}

__device__ __forceinline__ const float* e0_row(int c,
                                               const float* __restrict__ ue,
                                               const float* __restrict__ ie) {
    return (c < N_USER) ? &ue[(size_t)c * D] : &ie[(size_t)(c - N_USER) * D];
}

// ---------------------------------------------------------------------------
// Kernel 1: bits = 0 (ws is poisoned 0xAA every call)
// ---------------------------------------------------------------------------
__global__ void k_clear(unsigned int* __restrict__ bits) {
    int i = blockIdx.x * blockDim.x + threadIdx.x;
    if (i < NBW) bits[i] = 0u;
}

// ---------------------------------------------------------------------------
// Kernel 2: claim rows via atomicOr on the bitmap (old-value tells winner).
// 1 thread per slot. Winner stores rowslot[r]=slot and zeroes cnt[slot].
// ---------------------------------------------------------------------------
__global__ void k_mark(const int* __restrict__ users,
                       const int* __restrict__ pos,
                       const int* __restrict__ neg,
                       unsigned int* __restrict__ bits,
                       int* __restrict__ rowslot,
                       int* __restrict__ cnt) {
    int slot = blockIdx.x * blockDim.x + threadIdx.x;
    if (slot >= NSLOT) return;
    int r = slot_row(slot, users, pos, neg);
    unsigned int bit = 1u << (r & 31);
    unsigned int old = atomicOr(&bits[r >> 5], bit);
    if (!(old & bit)) {                   // this slot won the row
        rowslot[r] = slot;
        cnt[slot]  = 0;
    }
}

// ---------------------------------------------------------------------------
// Kernel 3: stream all edges (int4/float4, 2-deep pipelined); LDS bitmap
// filter; hits (~7.5%) do one random rowslot load + 4 B cnt atomic + 8 B
// packed bucket store. Overflow (never) just drops; k_fin rescans exactly.
// 1024 blocks x 512 thr = full 32-wave/CU occupancy (LDS 4x18.75 KB = 75 KB).
// ---------------------------------------------------------------------------
__global__ __launch_bounds__(512)
void k_scan(const int*   __restrict__ adj_row,
            const int*   __restrict__ adj_col,
            const float* __restrict__ adj_val,
            const unsigned int* __restrict__ bits,
            const int*   __restrict__ rowslot,
            int*   __restrict__ cnt,
            int2*  __restrict__ bcv) {
    __shared__ unsigned int sbits[NBW];
    {   // cooperative 16 B copy of the bitmap into LDS (NBW/4 = 1172)
        const int4* gb = (const int4*)bits;
        int4* sb = (int4*)sbits;
        for (int i = threadIdx.x; i < NBW / 4; i += blockDim.x) sb[i] = gb[i];
    }
    __syncthreads();

    int tid = blockIdx.x * blockDim.x + threadIdx.x;
    int nth = gridDim.x * blockDim.x;
    const int4*   row4 = (const int4*)adj_row;
    const int4*   col4 = (const int4*)adj_col;
    const float4* val4 = (const float4*)adj_val;

    #define PROC(RR, CC, VV)                                                    \
    {                                                                           \
        unsigned int w = sbits[(RR) >> 5];                                      \
        if ((w >> ((RR) & 31)) & 1u) {                                          \
            int s = rowslot[RR];                                                \
            int idx = atomicAdd(&cnt[s], 1);                                    \
            if (idx < CAP)                                                      \
                bcv[(size_t)s * CAP + idx] = make_int2(CC, __float_as_int(VV)); \
        }                                                                       \
    }

    int g = tid;
    if (g >= NQ) return;
    int4   r = row4[g];
    int4   c = col4[g];
    float4 v = val4[g];
    for (;;) {
        int gn = g + nth;
        bool more = gn < NQ;
        int4 rn, cn; float4 vn;
        if (more) { rn = row4[gn]; cn = col4[gn]; vn = val4[gn]; }
        PROC(r.x, c.x, v.x)
        PROC(r.y, c.y, v.y)
        PROC(r.z, c.z, v.z)
        PROC(r.w, c.w, v.w)
        if (!more) break;
        g = gn; r = rn; c = cn; v = vn;
    }
    #undef PROC
}

// ---------------------------------------------------------------------------
// Kernel 4: one wave per slot. EVERY slot (owner or duplicate) accumulates
// its row from the owner's bucket and writes out directly — no accd array.
// Lane layout: grp = lane>>4 picks the bucket entry (16 in flight/iter),
// sub = lane&15 picks the float4 of the 256 B row. shfl_xor(16,32) reduce.
// out[slot] = 0.25*e0[r] + 0.75*sum
// ---------------------------------------------------------------------------
__global__ void k_fin(const int* __restrict__ users,
                      const int* __restrict__ pos,
                      const int* __restrict__ neg,
                      const int* __restrict__ rowslot,
                      const int* __restrict__ cnt,
                      const int2* __restrict__ bcv,
                      const int*   __restrict__ adj_row,
                      const int*   __restrict__ adj_col,
                      const float* __restrict__ adj_val,
                      const float* __restrict__ ue,
                      const float* __restrict__ ie,
                      float* __restrict__ out) {
    int slot = (blockIdx.x * blockDim.x + threadIdx.x) >> 6;
    int lane = threadIdx.x & 63;
    if (slot >= NSLOT) return;
    int r = slot_row(slot, users, pos, neg);
    int owner = rowslot[r];
    int n = cnt[owner];
    int sub = lane & 15, grp = lane >> 4;
    float4 a = make_float4(0.f, 0.f, 0.f, 0.f);

    if (n <= CAP) {
        const int2* bb = &bcv[(size_t)owner * CAP];
        for (int i = 0; i < n; i += 16) {
            int m  = n - 1;
            int e0 = i + grp, e1 = e0 + 4, e2 = e0 + 8, e3 = e0 + 12;
            int2 p0 = bb[min(e0, m)];
            int2 p1 = bb[min(e1, m)];
            int2 p2 = bb[min(e2, m)];
            int2 p3 = bb[min(e3, m)];
            float4 x0 = ((const float4*)e0_row(p0.x, ue, ie))[sub];
            float4 x1 = ((const float4*)e0_row(p1.x, ue, ie))[sub];
            float4 x2 = ((const float4*)e0_row(p2.x, ue, ie))[sub];
            float4 x3 = ((const float4*)e0_row(p3.x, ue, ie))[sub];
            float v0 = (e0 < n) ? __int_as_float(p0.y) : 0.f;
            float v1 = (e1 < n) ? __int_as_float(p1.y) : 0.f;
            float v2 = (e2 < n) ? __int_as_float(p2.y) : 0.f;
            float v3 = (e3 < n) ? __int_as_float(p3.y) : 0.f;
            a.x += v0 * x0.x; a.y += v0 * x0.y; a.z += v0 * x0.z; a.w += v0 * x0.w;
            a.x += v1 * x1.x; a.y += v1 * x1.y; a.z += v1 * x1.z; a.w += v1 * x1.w;
            a.x += v2 * x2.x; a.y += v2 * x2.y; a.z += v2 * x2.z; a.w += v2 * x2.w;
            a.x += v3 * x3.x; a.y += v3 * x3.y; a.z += v3 * x3.z; a.w += v3 * x3.w;
        }
    } else {
        // statistically impossible (P < 1e-40) bucket overflow: exact rescan
        for (int e = grp; e < NNZ; e += 4) {
            if (adj_row[e] == r) {
                float v = adj_val[e];
                float4 x = ((const float4*)e0_row(adj_col[e], ue, ie))[sub];
                a.x += v * x.x; a.y += v * x.y; a.z += v * x.z; a.w += v * x.w;
            }
        }
    }

    a.x += __shfl_xor(a.x, 16); a.y += __shfl_xor(a.y, 16);
    a.z += __shfl_xor(a.z, 16); a.w += __shfl_xor(a.w, 16);
    a.x += __shfl_xor(a.x, 32); a.y += __shfl_xor(a.y, 32);
    a.z += __shfl_xor(a.z, 32); a.w += __shfl_xor(a.w, 32);

    if (grp == 0) {
        float4 e = ((const float4*)e0_row(r, ue, ie))[sub];
        float4* o = (float4*)&out[(size_t)slot * D];
        o[sub] = make_float4(0.25f * e.x + 0.75f * a.x,
                             0.25f * e.y + 0.75f * a.y,
                             0.25f * e.z + 0.75f * a.z,
                             0.25f * e.w + 0.75f * a.w);
    }
}

// ---------------------------------------------------------------------------
extern "C" void kernel_launch(void* const* d_in, const int* in_sizes, int n_in,
                              void* d_out, int out_size, void* d_ws, size_t ws_size,
                              hipStream_t stream) {
    const int*   users   = (const int*)  d_in[0];
    const int*   pos     = (const int*)  d_in[1];
    const int*   neg     = (const int*)  d_in[2];
    const float* ue      = (const float*)d_in[5];
    const float* ie      = (const float*)d_in[6];
    const int*   adj_row = (const int*)  d_in[7];
    const int*   adj_col = (const int*)  d_in[8];
    const float* adj_val = (const float*)d_in[9];
    float*       out     = (float*)      d_out;

    char* w = (char*)d_ws;
    int*          rowslot = (int*)w;          w += (size_t)NTOT * sizeof(int);
    unsigned int* bits    = (unsigned int*)w; w += (size_t)NBW * sizeof(unsigned int);
    int*          cnt     = (int*)w;          w += (size_t)NSLOT * sizeof(int);
    int2*         bcv     = (int2*)w;         /* NSLOT * CAP int2 */

    k_clear<<<(NBW + 255) / 256, 256, 0, stream>>>(bits);
    k_mark <<<(NSLOT + 255) / 256, 256, 0, stream>>>(users, pos, neg,
                                                     bits, rowslot, cnt);
    k_scan <<<1024, 512, 0, stream>>>(adj_row, adj_col, adj_val,
                                      bits, rowslot, cnt, bcv);
    k_fin  <<<(NSLOT * 64 + 255) / 256, 256, 0, stream>>>(users, pos, neg,
                                                          rowslot, cnt, bcv,
                                                          adj_row, adj_col, adj_val,
                                                          ue, ie, out);
}

// Round 8
// 156.052 us; speedup vs baseline: 1.9482x; 1.0174x over previous
//
#include <hip/hip_runtime.h>

#define N_USER 100000
#define N_ITEM 50000
#define NTOT   150000
#define D      64
#define NNZ    4000000
#define NQ     (NNZ / 4)
#define B      2048
#define NEG    8192
#define NSLOT  (B + B + NEG)        /* 12288 output rows */
#define CAP    128                  /* deg ~ Poisson(26.7); P(>=128) < 1e-40 */
#define NBW    ((NTOT + 31) / 32)   /* 4688 bitmap words (18.75 KB) */

typedef int   vint4   __attribute__((ext_vector_type(4)));
typedef float vfloat4 __attribute__((ext_vector_type(4)));

__device__ __forceinline__ int slot_row(int slot,
                                        const int* __restrict__ users,
                                        const int* __restrict__ pos,
                                        const int* __restrict__ neg) {
    if (slot < B)     return users[slot];
    if (slot < 2 * B) return N_USER + pos[slot - B];
    return N_USER + neg[slot - 2 * B];
}

__device__ __forceinline__ const float* e0_row(int c,
                                               const float* __restrict__ ue,
                                               const float* __restrict__ ie) {
    return (c < N_USER) ? &ue[(size_t)c * D] : &ie[(size_t)(c - N_USER) * D];
}

// ---------------------------------------------------------------------------
// Kernel 1: bits = 0 (ws is poisoned 0xAA every call)
// ---------------------------------------------------------------------------
__global__ void k_clear(unsigned int* __restrict__ bits) {
    int i = blockIdx.x * blockDim.x + threadIdx.x;
    if (i < NBW) bits[i] = 0u;
}

// ---------------------------------------------------------------------------
// Kernel 2: claim rows via atomicOr on the bitmap; the winner zeroes the
// row's bucket counter. 1 thread per slot; buckets are row-indexed so no
// slot->row indirection exists anywhere.
// ---------------------------------------------------------------------------
__global__ void k_mark(const int* __restrict__ users,
                       const int* __restrict__ pos,
                       const int* __restrict__ neg,
                       unsigned int* __restrict__ bits,
                       int* __restrict__ cntR) {
    int slot = blockIdx.x * blockDim.x + threadIdx.x;
    if (slot >= NSLOT) return;
    int r = slot_row(slot, users, pos, neg);
    unsigned int bit = 1u << (r & 31);
    unsigned int old = atomicOr(&bits[r >> 5], bit);
    if (!(old & bit)) cntR[r] = 0;        // winner zeroes the row counter
}

// ---------------------------------------------------------------------------
// Kernel 3: stream all edges (non-temporal dwordx4, 2-deep pipelined);
// LDS bitmap filter; hit path is just {4 B cnt atomic -> packed 8 B store},
// no dependent random load. 512 blocks x 1024 thr = 32 waves/CU.
// Overflow (statistically impossible) drops; k_fin rescans exactly.
// ---------------------------------------------------------------------------
__global__ __launch_bounds__(1024)
void k_scan(const int*   __restrict__ adj_row,
            const int*   __restrict__ adj_col,
            const float* __restrict__ adj_val,
            const unsigned int* __restrict__ bits,
            int*   __restrict__ cntR,
            int2*  __restrict__ bcv) {
    __shared__ unsigned int sbits[NBW];
    {   // cooperative 16 B copy of the bitmap into LDS (NBW/4 = 1172)
        const vint4* gb = (const vint4*)bits;
        vint4* sb = (vint4*)sbits;
        for (int i = threadIdx.x; i < NBW / 4; i += blockDim.x) sb[i] = gb[i];
    }
    __syncthreads();

    int tid = blockIdx.x * blockDim.x + threadIdx.x;
    int nth = gridDim.x * blockDim.x;
    const vint4*   row4 = (const vint4*)adj_row;
    const vint4*   col4 = (const vint4*)adj_col;
    const vfloat4* val4 = (const vfloat4*)adj_val;

    #define PROC(K)                                                              \
    {                                                                            \
        int RR = r[K];                                                           \
        unsigned int w = sbits[RR >> 5];                                         \
        if ((w >> (RR & 31)) & 1u) {                                             \
            int idx = atomicAdd(&cntR[RR], 1);                                   \
            if (idx < CAP)                                                       \
                bcv[(size_t)RR * CAP + idx] = make_int2(c[K], __float_as_int(v[K])); \
        }                                                                        \
    }

    int g = tid;
    if (g >= NQ) return;
    vint4   r = __builtin_nontemporal_load(&row4[g]);
    vint4   c = __builtin_nontemporal_load(&col4[g]);
    vfloat4 v = __builtin_nontemporal_load(&val4[g]);
    for (;;) {
        int gn = g + nth;
        bool more = gn < NQ;
        vint4 rn, cn; vfloat4 vn;
        if (more) {
            rn = __builtin_nontemporal_load(&row4[gn]);
            cn = __builtin_nontemporal_load(&col4[gn]);
            vn = __builtin_nontemporal_load(&val4[gn]);
        }
        PROC(0)
        PROC(1)
        PROC(2)
        PROC(3)
        if (!more) break;
        g = gn; r = rn; c = cn; v = vn;
    }
    #undef PROC
}

// ---------------------------------------------------------------------------
// Kernel 4: one wave per slot; accumulate the row's bucket, write out.
// Lane layout: grp = lane>>4 picks the bucket entry (16 in flight/iter),
// sub = lane&15 picks the float4 of the 256 B row. shfl_xor(16,32) reduce.
// out[slot] = 0.25*e0[r] + 0.75*sum
// ---------------------------------------------------------------------------
__global__ void k_fin(const int* __restrict__ users,
                      const int* __restrict__ pos,
                      const int* __restrict__ neg,
                      const int* __restrict__ cntR,
                      const int2* __restrict__ bcv,
                      const int*   __restrict__ adj_row,
                      const int*   __restrict__ adj_col,
                      const float* __restrict__ adj_val,
                      const float* __restrict__ ue,
                      const float* __restrict__ ie,
                      float* __restrict__ out) {
    int slot = (blockIdx.x * blockDim.x + threadIdx.x) >> 6;
    int lane = threadIdx.x & 63;
    if (slot >= NSLOT) return;
    int r = slot_row(slot, users, pos, neg);
    int n = cntR[r];
    int sub = lane & 15, grp = lane >> 4;
    float4 a = make_float4(0.f, 0.f, 0.f, 0.f);

    if (n <= CAP) {
        const int2* bb = &bcv[(size_t)r * CAP];
        for (int i = 0; i < n; i += 16) {
            int m  = n - 1;
            int e0 = i + grp, e1 = e0 + 4, e2 = e0 + 8, e3 = e0 + 12;
            int2 p0 = bb[min(e0, m)];
            int2 p1 = bb[min(e1, m)];
            int2 p2 = bb[min(e2, m)];
            int2 p3 = bb[min(e3, m)];
            float4 x0 = ((const float4*)e0_row(p0.x, ue, ie))[sub];
            float4 x1 = ((const float4*)e0_row(p1.x, ue, ie))[sub];
            float4 x2 = ((const float4*)e0_row(p2.x, ue, ie))[sub];
            float4 x3 = ((const float4*)e0_row(p3.x, ue, ie))[sub];
            float v0 = (e0 < n) ? __int_as_float(p0.y) : 0.f;
            float v1 = (e1 < n) ? __int_as_float(p1.y) : 0.f;
            float v2 = (e2 < n) ? __int_as_float(p2.y) : 0.f;
            float v3 = (e3 < n) ? __int_as_float(p3.y) : 0.f;
            a.x += v0 * x0.x; a.y += v0 * x0.y; a.z += v0 * x0.z; a.w += v0 * x0.w;
            a.x += v1 * x1.x; a.y += v1 * x1.y; a.z += v1 * x1.z; a.w += v1 * x1.w;
            a.x += v2 * x2.x; a.y += v2 * x2.y; a.z += v2 * x2.z; a.w += v2 * x2.w;
            a.x += v3 * x3.x; a.y += v3 * x3.y; a.z += v3 * x3.z; a.w += v3 * x3.w;
        }
    } else {
        // statistically impossible (P < 1e-40) bucket overflow: exact rescan
        for (int e = grp; e < NNZ; e += 4) {
            if (adj_row[e] == r) {
                float v = adj_val[e];
                float4 x = ((const float4*)e0_row(adj_col[e], ue, ie))[sub];
                a.x += v * x.x; a.y += v * x.y; a.z += v * x.z; a.w += v * x.w;
            }
        }
    }

    a.x += __shfl_xor(a.x, 16); a.y += __shfl_xor(a.y, 16);
    a.z += __shfl_xor(a.z, 16); a.w += __shfl_xor(a.w, 16);
    a.x += __shfl_xor(a.x, 32); a.y += __shfl_xor(a.y, 32);
    a.z += __shfl_xor(a.z, 32); a.w += __shfl_xor(a.w, 32);

    if (grp == 0) {
        float4 e = ((const float4*)e0_row(r, ue, ie))[sub];
        float4* o = (float4*)&out[(size_t)slot * D];
        o[sub] = make_float4(0.25f * e.x + 0.75f * a.x,
                             0.25f * e.y + 0.75f * a.y,
                             0.25f * e.z + 0.75f * a.z,
                             0.25f * e.w + 0.75f * a.w);
    }
}

// ---------------------------------------------------------------------------
extern "C" void kernel_launch(void* const* d_in, const int* in_sizes, int n_in,
                              void* d_out, int out_size, void* d_ws, size_t ws_size,
                              hipStream_t stream) {
    const int*   users   = (const int*)  d_in[0];
    const int*   pos     = (const int*)  d_in[1];
    const int*   neg     = (const int*)  d_in[2];
    const float* ue      = (const float*)d_in[5];
    const float* ie      = (const float*)d_in[6];
    const int*   adj_row = (const int*)  d_in[7];
    const int*   adj_col = (const int*)  d_in[8];
    const float* adj_val = (const float*)d_in[9];
    float*       out     = (float*)      d_out;

    char* w = (char*)d_ws;
    int*          cntR = (int*)w;          w += (size_t)NTOT * sizeof(int);        /* 600 KB */
    unsigned int* bits = (unsigned int*)w; w += (size_t)NBW * sizeof(unsigned int);/* 18.75 KB */
    int2*         bcv  = (int2*)w;         /* NTOT * CAP int2 = 153.6 MB */

    k_clear<<<(NBW + 255) / 256, 256, 0, stream>>>(bits);
    k_mark <<<(NSLOT + 255) / 256, 256, 0, stream>>>(users, pos, neg, bits, cntR);
    k_scan <<<512, 1024, 0, stream>>>(adj_row, adj_col, adj_val, bits, cntR, bcv);
    k_fin  <<<(NSLOT * 64 + 255) / 256, 256, 0, stream>>>(users, pos, neg,
                                                          cntR, bcv,
                                                          adj_row, adj_col, adj_val,
                                                          ue, ie, out);
}